// Round 16
// baseline (203.068 us; speedup 1.0000x reference)
//
#include <hip/hip_runtime.h>
#include <math.h>

// Wavelet scattering, T=16384.  R16: j2=2/q0 dropped to N'=4096 (input
// truncated at 4096 = 5.6 sigma_env; forward margin 3.8 sigma, same criterion
// as the passing j2=1@8192 class);  <=2048 classes run in 128-thread /
// 17.4KB blocks (8 blocks/CU, eight 2-wave barrier domains).
// 7 launches: fft_x -> o1a(8192) -> o1b(4096) -> o1c(<=2048)
//             -> o2a(j2=1@8192) -> o2b(4096) -> o2c(<=2048).

#define T_N   16384
#define NT    512
#define NTS   256
#define NTX   128
#define B_SZ  16
#define N1    64
#define NPAIR 224
#define FOLD_F 256
#define USTRIDE 8208
#define INV_N (1.0f/16384.0f)
#define TWO_PI 6.283185307179586f

typedef float v2f __attribute__((ext_vector_type(2)));

__device__ __forceinline__ int pad(int i) { return i + (i >> 4); }

__device__ __forceinline__ v2f cmulw(v2f a, v2f w){
  v2f n; n.x = -a.y; n.y = a.x;
  return w.x * a + w.y * n;
}
__device__ __forceinline__ constexpr int br4(int x){
  return ((x&1)<<3)|((x&2)<<1)|((x&4)>>1)|((x&8)>>3);
}
template<int LB>
__device__ __forceinline__ constexpr int brN(int x){
  int r=0;
  for(int i=0;i<LB;++i){ r=(r<<1)|((x>>i)&1); }
  return r;
}
__device__ __forceinline__ int rev4_14(int p){
  unsigned r = __brev((unsigned)p) >> 18;
  return (int)(((r & 0x2AAAu) >> 1) | ((r & 0x1555u) << 1));
}

// tw[r] = w^r via depth-4 product tree.
__device__ __forceinline__ void twiddle_tree(v2f w, v2f* tw){
  tw[0].x = 1.f; tw[0].y = 0.f;
  tw[1] = w;
  tw[2] = cmulw(w, w);
  tw[4] = cmulw(tw[2], tw[2]);
  tw[8] = cmulw(tw[4], tw[4]);
  tw[3] = cmulw(tw[2], w);
  tw[5] = cmulw(tw[4], w);
  tw[6] = cmulw(tw[4], tw[2]);
  tw[7] = cmulw(tw[4], tw[3]);
  tw[9]  = cmulw(tw[8], w);
  tw[10] = cmulw(tw[8], tw[2]);
  tw[11] = cmulw(tw[8], tw[3]);
  tw[12] = cmulw(tw[8], tw[4]);
  tw[13] = cmulw(tw[8], tw[5]);
  tw[14] = cmulw(tw[8], tw[6]);
  tw[15] = cmulw(tw[8], tw[7]);
}

// Generic fully-unrolled DFT of size 2^LOGNN (<=16); y[r] lands at a[brN(r)].
template<int SGN, int LOGNN>
__device__ __forceinline__ void dft_reg(v2f* a){
  constexpr int NN = 1<<LOGNN;
  static constexpr float C16[16] = {
    1.f, 0.98078528f, 0.92387953f, 0.83146961f, 0.70710678f, 0.55557023f,
    0.38268343f, 0.19509032f, 0.f, -0.19509032f, -0.38268343f, -0.55557023f,
    -0.70710678f, -0.83146961f, -0.92387953f, -0.98078528f };
  static constexpr float S16[16] = {
    0.f, 0.19509032f, 0.38268343f, 0.55557023f, 0.70710678f, 0.83146961f,
    0.92387953f, 0.98078528f, 1.f, 0.98078528f, 0.92387953f, 0.83146961f,
    0.70710678f, 0.55557023f, 0.38268343f, 0.19509032f };
#pragma unroll
  for (int m = NN/2; m >= 1; m >>= 1) {
#pragma unroll
    for (int base = 0; base < NN; base += 2*m) {
#pragma unroll
      for (int j = 0; j < m; ++j) {
        v2f u = a[base+j], v = a[base+j+m];
        a[base+j] = u + v;
        v2f w = u - v;
        const int ti = (j*16)/m;
        v2f tw; tw.x = C16[ti]; tw.y = (float)SGN * S16[ti];
        a[base+j+m] = cmulw(w, tw);
      }
    }
  }
}
template<int SGN>
__device__ __forceinline__ void dft16(v2f* a){ dft_reg<SGN,4>(a); }

// Full DIF super-stage radix-16 at stride M.
template<int SGN, int M, int LOGM>
__device__ __forceinline__ void super_dif16(v2f* d, int g)
{
  const int j = g & (M-1);
  const int base = ((g >> LOGM) << (LOGM+4)) | j;
  v2f* dp = d + pad(base);
  v2f a[16];
#pragma unroll
  for (int k = 0; k < 16; ++k) a[k] = dp[k*M + ((k*M)>>4)];
  dft16<SGN>(a);
  float sj, cj;
  __sincosf((float)SGN * (TWO_PI / (16.f*(float)M)) * (float)j, &sj, &cj);
  v2f w; w.x = cj; w.y = sj;
  v2f tw[16];
  twiddle_tree(w, tw);
  dp[0] = a[0];
#pragma unroll
  for (int r = 1; r < 16; ++r)
    dp[r*M + ((r*M)>>4)] = cmulw(a[br4(r)], tw[r]);
}

// SPARSE DIF super-stage: only taps [0,8) possibly nonzero (rest zeros).
template<int SGN, int M, int LOGM>
__device__ __forceinline__ void super_dif16_sp8(v2f* d, int g)
{
  static constexpr float CW[16] = { 1.f, 0.92387953f, 0.70710678f, 0.38268343f,
    0.f, -0.38268343f, -0.70710678f, -0.92387953f, -1.f, -0.92387953f,
    -0.70710678f, -0.38268343f, 0.f, 0.38268343f, 0.70710678f, 0.92387953f };
  static constexpr float SW[16] = { 0.f, 0.38268343f, 0.70710678f, 0.92387953f,
    1.f, 0.92387953f, 0.70710678f, 0.38268343f, 0.f, -0.38268343f,
    -0.70710678f, -0.92387953f, -1.f, -0.92387953f, -0.70710678f, -0.38268343f };
  const int j = g & (M-1);
  const int base = ((g >> LOGM) << (LOGM+4)) | j;
  v2f* dp = d + pad(base);
  v2f a[8];
#pragma unroll
  for (int m = 0; m < 8; ++m) a[m] = dp[m*M + ((m*M)>>4)];
  v2f y[16];
#pragma unroll
  for (int r0 = 0; r0 < 2; ++r0) {
    v2f z[8];
    z[0] = a[0];
#pragma unroll
    for (int m = 1; m < 8; ++m) {
      v2f w; w.x = CW[(m*r0)&15]; w.y = (float)SGN*SW[(m*r0)&15];
      z[m] = cmulw(a[m], w);
    }
    v2f E[4], O[4];
    {
      v2f e0=z[0]+z[4], e1=z[0]-z[4], o0=z[2]+z[6], o1=z[2]-z[6];
      v2f io; io.x=-(float)SGN*o1.y; io.y=(float)SGN*o1.x;
      E[0]=e0+o0; E[1]=e1+io; E[2]=e0-o0; E[3]=e1-io;
    }
    {
      v2f e0=z[1]+z[5], e1=z[1]-z[5], o0=z[3]+z[7], o1=z[3]-z[7];
      v2f io; io.x=-(float)SGN*o1.y; io.y=(float)SGN*o1.x;
      O[0]=e0+o0; O[1]=e1+io; O[2]=e0-o0; O[3]=e1-io;
    }
    constexpr float RT = 0.70710678f;
#pragma unroll
    for (int r1 = 0; r1 < 4; ++r1) {
      v2f w8;
      if (r1 == 0)      { w8.x = 1.f;  w8.y = 0.f; }
      else if (r1 == 1) { w8.x = RT;   w8.y = (float)SGN*RT; }
      else if (r1 == 2) { w8.x = 0.f;  w8.y = (float)SGN; }
      else              { w8.x = -RT;  w8.y = (float)SGN*RT; }
      v2f t = cmulw(O[r1], w8);
      y[2*r1 + r0]     = E[r1] + t;
      y[2*r1 + r0 + 8] = E[r1] - t;
    }
  }
  float sj, cj;
  __sincosf((float)SGN * (TWO_PI / (16.f*(float)M)) * (float)j, &sj, &cj);
  v2f w; w.x = cj; w.y = sj;
  v2f tw[16];
  twiddle_tree(w, tw);
  dp[0] = y[0];
#pragma unroll
  for (int r = 1; r < 16; ++r)
    dp[r*M + ((r*M)>>4)] = cmulw(y[r], tw[r]);
}

// Full DIT super-stage radix-16 at stride M.
template<int SGN, int M, int LOGM>
__device__ __forceinline__ void super_dit16(v2f* d, int g)
{
  const int j = g & (M-1);
  const int base = ((g >> LOGM) << (LOGM+4)) | j;
  v2f* dp = d + pad(base);
  float sj, cj;
  __sincosf((float)SGN * (TWO_PI / (16.f*(float)M)) * (float)j, &sj, &cj);
  v2f w; w.x = cj; w.y = sj;
  v2f tw[16];
  twiddle_tree(w, tw);
  v2f a[16];
  a[0] = dp[0];
#pragma unroll
  for (int k = 1; k < 16; ++k)
    a[k] = cmulw(dp[k*M + ((k*M)>>4)], tw[k]);
  dft16<SGN>(a);
#pragma unroll
  for (int r = 0; r < 16; ++r) dp[r*M + ((r*M)>>4)] = a[br4(r)];
}

// Generic output-pruned final DIT16 at M1 = 2^LOGM1: outputs r < RMAX.
template<int SGN, int LOGM1, int RMAX, bool JLIM>
__device__ __forceinline__ void final_prune(v2f* ds, int t)
{
  static constexpr float CW[16] = { 1.f, 0.92387953f, 0.70710678f, 0.38268343f,
    0.f, -0.38268343f, -0.70710678f, -0.92387953f, -1.f, -0.92387953f,
    -0.70710678f, -0.38268343f, 0.f, 0.38268343f, 0.70710678f, 0.92387953f };
  static constexpr float SW[16] = { 0.f, 0.38268343f, 0.70710678f, 0.92387953f,
    1.f, 0.92387953f, 0.70710678f, 0.38268343f, 0.f, -0.38268343f,
    -0.70710678f, -0.92387953f, -1.f, -0.92387953f, -0.70710678f, -0.38268343f };
  constexpr int M1 = 1<<LOGM1;
  const int j = t;
  if (JLIM && j >= 256) return;
  v2f* dp = ds + j + (j>>4);
  float sj, cj;
  __sincosf((float)SGN * (TWO_PI / (16.f*(float)M1)) * (float)j, &sj, &cj);
  v2f w; w.x = cj; w.y = sj;
  v2f tw[16];
  twiddle_tree(w, tw);
  v2f b[16];
  b[0] = dp[0];
#pragma unroll
  for (int k = 1; k < 16; ++k)
    b[k] = cmulw(dp[k*M1 + ((k*M1)>>4)], tw[k]);
#pragma unroll
  for (int r = 0; r < RMAX; ++r) {
    v2f acc = b[0];
#pragma unroll
    for (int k = 1; k < 16; ++k) {
      v2f wc; wc.x = CW[(r*k)&15]; wc.y = (float)SGN*SW[(r*k)&15];
      acc += cmulw(b[k], wc);
    }
    dp[r*M1 + ((r*M1)>>4)] = acc;
  }
}

// DIF chain descending (barrier after each stage).
template<int SGN, int LOGM>
__device__ __forceinline__ void dif_chain(v2f* ds, int t){
  super_dif16<SGN, (1<<LOGM), LOGM>(ds, t);
  __syncthreads();
  if constexpr (LOGM > 4) dif_chain<SGN, LOGM-4>(ds, t);
}
// DIT chain ascending up to (excluding) LOGTOP.
template<int SGN, int LOGM, int LOGTOP>
__device__ __forceinline__ void dit_chain(v2f* ds, int t){
  super_dit16<SGN, (1<<LOGM), LOGM>(ds, t);
  __syncthreads();
  if constexpr (LOGM + 4 < LOGTOP) dit_chain<SGN, LOGM+4, LOGTOP>(ds, t);
}

// Generic mid: per contiguous-16 (thread t): inverse DFT_MM -> |.|/T -> fwd DFT_MM.
template<int LOGMM>
__device__ __forceinline__ void mid_generic(v2f* ds, int t)
{
  constexpr int MM = 1<<LOGMM;
  v2f* dp = ds + 17*t;
#pragma unroll
  for (int q = 0; q < 16/MM; ++q) {
    v2f a[MM];
#pragma unroll
    for (int i = 0; i < MM; ++i) a[i] = dp[q*MM+i];
    dft_reg<+1,LOGMM>(a);
    v2f m[MM];
#pragma unroll
    for (int r = 0; r < MM; ++r) {
      v2f y = a[brN<LOGMM>(r)];
      m[r].x = INV_N * sqrtf(y.x*y.x + y.y*y.y);
      m[r].y = 0.f;
    }
    dft_reg<-1,LOGMM>(m);
#pragma unroll
    for (int k = 0; k < MM; ++k) dp[q*MM+k] = m[brN<LOGMM>(k)];
  }
}

// Generic decimated pipeline body, LOGN in {9..13}.  K1ST = 16 (full) or 8.
template<int LOGN, int RMAX, bool JL, int K1ST>
__device__ __forceinline__ void o2_body(v2f* ds, int t)
{
  constexpr int LOGM1 = LOGN-4;
  if constexpr (K1ST == 16) super_dif16<+1, (1<<LOGM1), LOGM1>(ds, t);
  else                      super_dif16_sp8<+1, (1<<LOGM1), LOGM1>(ds, t);
  __syncthreads();
  dif_chain<+1, LOGM1-4>(ds, t);
  constexpr int LOGMM = ((LOGM1-5)%4)+1;
  mid_generic<LOGMM>(ds, t);
  __syncthreads();
  dit_chain<-1, LOGMM, LOGM1>(ds, t);
  final_prune<-1, LOGM1, RMAX, JL>(ds, t);
  __syncthreads();
}

// Generic fold: SEGT = 64*PERK threads, scale applied at write.
template<int PERK>
__device__ __forceinline__ void fold_generic(const v2f* ds, const float* __restrict__ phi,
                                             float* outp, int t, float scale)
{
  const int k = t / PERK, g = t % PERK;
  float sv, cv, ss, cs;
  __sincosf((TWO_PI/64.f) * (float)((g*k) & 63), &sv, &cv);
  __sincosf((TWO_PI/64.f) * (float)((PERK*k) & 63), &ss, &cs);
  float acc = 0.f;
#pragma unroll
  for (int m = 0; m < 256/PERK; ++m) {
    const int f = g + PERK*m;
    v2f u = ds[f + (f>>4)];
    float wgt = phi[f] * ((f == 0) ? 1.f : 2.f);
    acc += wgt * (u.x*cv - u.y*sv);
    float nc = cv*cs - sv*ss, ns = cv*ss + sv*cs;
    cv = nc; sv = ns;
  }
#pragma unroll
  for (int o = 1; o < PERK; o <<= 1) acc += __shfl_xor(acc, o);
  if (g == 0) outp[k] = acc * scale;
}

// Fold for N'=512 pipelines (SEGT=32): exact 256->64 pre-fold, then 64-pt DFT.
// Scratch in free LDS slots [384, 448) of the pipeline.
__device__ __forceinline__ void fold32(v2f* ds, const float* __restrict__ phi,
                                       float* outp, int t, float scale, bool valid)
{
#pragma unroll
  for (int h = 0; h < 2; ++h) {
    const int g = t + 32*h;
    v2f acc; acc.x = 0.f; acc.y = 0.f;
#pragma unroll
    for (int m = 0; m < 4; ++m) {
      const int f = g + 64*m;
      v2f u = ds[f + (f>>4)];
      float wgt = phi[f] * ((f == 0) ? 1.f : 2.f);
      acc += wgt * u;
    }
    const int s = 384 + g;
    ds[s + (s>>4)] = acc;
  }
  __syncthreads();
  if (valid) {
#pragma unroll
    for (int h = 0; h < 2; ++h) {
      const int k = t + 32*h;
      float ss, cs;
      __sincosf((TWO_PI/64.f) * (float)k, &ss, &cs);
      float cv = 1.f, sv = 0.f, acc = 0.f;
      for (int g = 0; g < 64; ++g) {
        const int s = 384 + g;
        v2f V = ds[s + (s>>4)];
        acc += V.x*cv - V.y*sv;
        float nc = cv*cs - sv*ss, ns = cv*ss + sv*cs;
        cv = nc; sv = ns;
      }
      outp[k] = acc * scale;
    }
  }
}

// Reference pair index (j1-major, valid j2 > j1/8).
__device__ __forceinline__ int pair_index(int j1, int j2)
{
  const int q = j1 >> 3;
  return 8*(7*q - (q*(q-1))/2) + (j1 & 7)*(7 - q) + (j2 - q - 1);
}

// psi2 band widths W(j2) = ceil(4.5 * 5734.4 * 2^-j2)
__device__ __constant__ int WTAB[8]  = {16384, 12903, 6452, 3226, 1613, 807, 404, 202};
// U1h truncation per j1-octave q: tb = ~0.8*c(8q) = 6.3 sigma_env.
__device__ __constant__ int TBTAB[8] = {4600, 2300, 1152, 576, 292, 148, 76, 40};

// ---- radix-4 float2 path for k_fft_x ----
__device__ __forceinline__ float2 f2add(float2 a, float2 b){ return make_float2(a.x+b.x, a.y+b.y); }
__device__ __forceinline__ float2 f2sub(float2 a, float2 b){ return make_float2(a.x-b.x, a.y-b.y); }
__device__ __forceinline__ float2 cmul_cs(float2 a, float c, float s){
  return make_float2(a.x*c - a.y*s, a.x*s + a.y*c);
}
__device__ void dif_sweep(float2* d, int tid, float sgn, int mb_hi, int mb_lo)
{
  const float ang = sgn * (TWO_PI / (float)T_N);
  for (int mbits = mb_hi; mbits >= mb_lo; mbits -= 2) {
    const int M = 1 << mbits;
#pragma unroll 8
    for (int v = tid; v < T_N/4; v += NT) {
      const int j = v & (M-1);
      const int base = ((v >> mbits) << (mbits+2)) | j;
      const int i0 = pad(base), i1 = pad(base+M), i2 = pad(base+2*M), i3 = pad(base+3*M);
      float2 a0=d[i0], a1=d[i1], a2=d[i2], a3=d[i3];
      float2 t0=f2add(a0,a2), t1=f2sub(a0,a2), t2=f2add(a1,a3), t3=f2sub(a1,a3);
      float2 y0=f2add(t0,t2), y2=f2sub(t0,t2);
      float2 y1=make_float2(t1.x - sgn*t3.y, t1.y + sgn*t3.x);
      float2 y3=make_float2(t1.x + sgn*t3.y, t1.y - sgn*t3.x);
      float s1,c1;
      __sincosf(ang * (float)(j << (12-mbits)), &s1, &c1);
      float c2=c1*c1-s1*s1, s2=2.f*c1*s1;
      float c3=c1*c2-s1*s2, s3=c1*s2+s1*c2;
      d[i0]=y0;
      d[i1]=cmul_cs(y1,c1,s1);
      d[i2]=cmul_cs(y2,c2,s2);
      d[i3]=cmul_cs(y3,c3,s3);
    }
    __syncthreads();
  }
}
__device__ void fold_store8(const float2* d, const float* __restrict__ phi, float* outp, int tid)
{
  const int k = tid >> 3, g = tid & 7;
  float acc = 0.f;
  for (int f = g; f < FOLD_F; f += 8) {
    float2 u = d[pad(f)];
    float w = phi[f] * ((f == 0) ? 1.f : 2.f);
    float sv, cv;
    __sincosf((TWO_PI/64.f) * (float)((f*k) & 63), &sv, &cv);
    acc += w * (u.x*cv - u.y*sv);
  }
  acc += __shfl_xor(acc, 1);
  acc += __shfl_xor(acc, 2);
  acc += __shfl_xor(acc, 4);
  if (g == 0) outp[k] = acc * INV_N;
}

// K1: xh = FFT(x) + S0 fold.
__global__ void __launch_bounds__(NT) k_fft_x(const float* __restrict__ x, const float* __restrict__ phi,
                                              float2* __restrict__ xh, float* __restrict__ out)
{
  extern __shared__ char smem[];
  float2* d = (float2*)smem;
  const int tid = threadIdx.x;
  const int b = blockIdx.x;
  const float* xr = x + b * T_N;
  for (int i = tid; i < T_N; i += NT) d[pad(i)] = make_float2(xr[i], 0.f);
  __syncthreads();
  dif_sweep(d, tid, -1.f, 12, 0);
  for (int p = tid; p < T_N; p += NT) {
    int r = rev4_14(p);
    if (p < r) { int ip = pad(p), ir = pad(r); float2 t = d[ip]; d[ip] = d[ir]; d[ir] = t; }
  }
  __syncthreads();
  float2* xrow = xh + (size_t)b * T_N;
  for (int i = tid; i < T_N; i += NT) xrow[i] = d[pad(i)];
  fold_store8(d, phi, out + b * 64, tid);
}

// Decimated order-1 body: demodulated band [lo,hi) at slots [0,W).
template<int LOGN>
__device__ __forceinline__ void o1_dec_body(v2f* sm, int sub, int t, int j1, int b,
    const float2* __restrict__ xh, const float* __restrict__ psi1,
    const float* __restrict__ phi, float2* __restrict__ u1h, float* __restrict__ out)
{
  constexpr int N = 1<<LOGN, SEGT = N/16;
  v2f* ds = sm + sub*N + ((sub*N)>>4);
  const float c = 5734.4f * exp2f(-0.125f*(float)j1);
  const int lo = max(0, (int)(0.36f*c));
  const int hi = min(T_N, (int)(1.64f*c)+2);
  const int W = hi - lo;
  const float2* xrow = xh + (size_t)b * T_N;
  const float* prow = psi1 + j1 * T_N;
#pragma unroll
  for (int s = 0; s < 16; ++s) {
    int f = t + s*SEGT;
    v2f z; z.x = 0.f; z.y = 0.f;
    if (f < W) { float2 xv = xrow[lo+f]; float p = prow[lo+f]; z.x = xv.x*p; z.y = xv.y*p; }
    ds[f + (f>>4)] = z;
  }
  __syncthreads();
  constexpr int RM = (LOGN == 9) ? 10 : 9;
  o2_body<LOGN, RM, false, 16>(ds, t);
  const int tb = TBTAB[(j1>>3) & 7];
  const float R = (float)(T_N >> LOGN);
  float2* urow = u1h + (size_t)(b*N1 + j1) * USTRIDE;
  for (int i = t; i < tb; i += SEGT) {
    v2f u = ds[i + (i>>4)];
    urow[i] = make_float2(R*u.x, R*u.y);
  }
  float* outp = out + 1024 + (size_t)(b*N1 + j1)*64;
  if constexpr (SEGT >= 64) fold_generic<SEGT/64>(ds, phi, outp, t, 1.f/(float)N);
  else                      fold32(ds, phi, outp, t, 1.f/(float)N, true);
}

// K2a (order-1, N'=8192): j1 0-7, 1 ppl/blk, 512 thr. 128 blocks.
__global__ void __launch_bounds__(NT, 4) k_o1a(const float2* __restrict__ xh, const float* __restrict__ psi1,
                                               const float* __restrict__ phi, float2* __restrict__ u1h,
                                               float* __restrict__ out)
{
  extern __shared__ char smem[];
  o1_dec_body<13>((v2f*)smem, 0, threadIdx.x, blockIdx.x / B_SZ, blockIdx.x % B_SZ,
                  xh, psi1, phi, u1h, out);
}

// K2b (order-1, N'=4096): j1 8-15, 1 ppl/blk, 256 thr. 128 blocks.
__global__ void __launch_bounds__(NTS, 4) k_o1b(const float2* __restrict__ xh, const float* __restrict__ psi1,
                                                const float* __restrict__ phi, float2* __restrict__ u1h,
                                                float* __restrict__ out)
{
  extern __shared__ char smem[];
  o1_dec_body<12>((v2f*)smem, 0, threadIdx.x, 8 + blockIdx.x / B_SZ, blockIdx.x % B_SZ,
                  xh, psi1, phi, u1h, out);
}

// K2c (order-1, N' <= 2048): 128-thread / 17.4KB blocks, 8 blocks/CU.
// 20 groups/batch: grp 0-7: q=2 2048 (1 ppl/blk) | 8-11: q=3 1024 (2)
// | 12-19: q>=4 512 (4).
__global__ void __launch_bounds__(NTX, 4) k_o1c(const float2* __restrict__ xh, const float* __restrict__ psi1,
                                                const float* __restrict__ phi, float2* __restrict__ u1h,
                                                float* __restrict__ out)
{
  extern __shared__ char smem[];
  v2f* sm = (v2f*)smem;
  const int grp = blockIdx.x / B_SZ, b = blockIdx.x % B_SZ;
  const int tid = threadIdx.x;
  if (grp < 8) {
    o1_dec_body<11>(sm, 0, tid, 16 + grp, b, xh, psi1, phi, u1h, out);
  } else if (grp < 12) {
    const int sub = tid >> 6;
    o1_dec_body<10>(sm, sub, tid & 63, 24 + (grp-8)*2 + sub, b, xh, psi1, phi, u1h, out);
  } else {
    const int sub = tid >> 5;
    o1_dec_body<9>(sm, sub, tid & 31, 32 + (grp-12)*4 + sub, b, xh, psi1, phi, u1h, out);
  }
}

// Decimated order-2 body (S2 fold only).  Input support min(W, tb, N) — input
// past N is >= 5.6 sigma_env of the U1 envelope for affected classes.
template<int LOGN, int K1ST>
__device__ __forceinline__ void o2_cls_body(v2f* sm, int sub, int t, int b, int j1, int j2, bool valid,
    const float2* __restrict__ u1h, const float* __restrict__ psi2,
    const float* __restrict__ phi, float* __restrict__ out)
{
  constexpr int N = 1<<LOGN, SEGT = N/16;
  v2f* ds = sm + sub*N + ((sub*N)>>4);
  const int W  = WTAB[j2 & 7];
  const int tb = TBTAB[(j1 >> 3) & 7];
  const int lim = min(min(W, tb), N);
  const float2* urow = u1h + (size_t)(b * N1 + j1) * USTRIDE;
  const float* prow = psi2 + j2 * T_N;
#pragma unroll
  for (int s = 0; s < 16; ++s) {
    int f = t + s*SEGT;
    v2f z; z.x = 0.f; z.y = 0.f;
    if (valid && f < lim) { float2 u = urow[f]; float ps = prow[f]; z.x = u.x*ps; z.y = u.y*ps; }
    ds[f + (f>>4)] = z;
  }
  __syncthreads();
  constexpr int RM = ((1<<(LOGN-4)) >= 256) ? 1 : (256 >> (LOGN-4));
  constexpr bool JL = ((1<<(LOGN-4)) > 256);
  o2_body<LOGN, RM, JL, K1ST>(ds, t);
  float* outp = out + 66560 + (size_t)(b * NPAIR + pair_index(j1, j2)) * 64;
  if constexpr (SEGT >= 64) { if (valid) fold_generic<SEGT/64>(ds, phi, outp, t, 1.f/(float)N); }
  else                      fold32(ds, phi, outp, t, 1.f/(float)N, valid);
}

// K3a (order-2, j2=1 @ N'=8192): j1 0-7, 512 thr, sp8 first stage. 128 blocks.
__global__ void __launch_bounds__(NT, 4) k_o2a(const float2* __restrict__ u1h, const float* __restrict__ psi2,
                                               const float* __restrict__ phi, float* __restrict__ out)
{
  extern __shared__ char smem[];
  o2_cls_body<13,8>((v2f*)smem, 0, threadIdx.x, blockIdx.x % B_SZ, blockIdx.x / B_SZ, 1, true,
                    u1h, psi2, phi, out);
}

// K3b (order-2, N'=4096): 256 thr, 1 ppl/blk. 40 groups/batch:
// grp 0-7: j2=2 q=0 (lim clamped to 4096) | 8-15: j2=2 q=1 | 16-39: j2=3.
__global__ void __launch_bounds__(NTS, 4) k_o2b(const float2* __restrict__ u1h, const float* __restrict__ psi2,
                                                const float* __restrict__ phi, float* __restrict__ out)
{
  extern __shared__ char smem[];
  v2f* sm = (v2f*)smem;
  const int grp = blockIdx.x / B_SZ, b = blockIdx.x % B_SZ;
  if (grp < 16) {
    o2_cls_body<12,16>(sm, 0, threadIdx.x, b, grp, 2, true, u1h, psi2, phi, out);
  } else {
    o2_cls_body<12,16>(sm, 0, threadIdx.x, b, grp - 16, 3, true, u1h, psi2, phi, out);
  }
}

// K3c (order-2, N' <= 2048): 128-thread / 17.4KB blocks, 8 blocks/CU.
// 78 groups/batch: grp 0-31: j2=4 2048 (1/blk) | 32-51: j2=5 1024 (2/blk)
// | 52-63: j2=6 512 (4/blk) | 64-77: j2=7 512 (4/blk, j1 0-55 valid).
__global__ void __launch_bounds__(NTX, 4) k_o2c(const float2* __restrict__ u1h, const float* __restrict__ psi2,
                                                const float* __restrict__ phi, float* __restrict__ out)
{
  extern __shared__ char smem[];
  v2f* sm = (v2f*)smem;
  const int grp = blockIdx.x / B_SZ, b = blockIdx.x % B_SZ;
  const int tid = threadIdx.x;
  if (grp < 32) {
    o2_cls_body<11,16>(sm, 0, tid, b, grp, 4, true, u1h, psi2, phi, out);
  } else if (grp < 52) {
    const int sub = tid >> 6;
    o2_cls_body<10,16>(sm, sub, tid & 63, b, (grp-32)*2 + sub, 5, true, u1h, psi2, phi, out);
  } else if (grp < 64) {
    const int sub = tid >> 5;
    o2_cls_body<9,16>(sm, sub, tid & 31, b, (grp-52)*4 + sub, 6, true, u1h, psi2, phi, out);
  } else {
    const int sub = tid >> 5;
    o2_cls_body<9,8>(sm, sub, tid & 31, b, (grp-64)*4 + sub, 7, true, u1h, psi2, phi, out);
  }
}

extern "C" void kernel_launch(void* const* d_in, const int* in_sizes, int n_in,
                              void* d_out, int out_size, void* d_ws, size_t ws_size,
                              hipStream_t stream)
{
  const float* x    = (const float*)d_in[0];
  const float* psi1 = (const float*)d_in[1];
  const float* psi2 = (const float*)d_in[2];
  const float* phi  = (const float*)d_in[3];
  float* out = (float*)d_out;

  float2* xh  = (float2*)d_ws;
  float2* u1h = xh + (size_t)B_SZ * T_N;

  const size_t lds_h = (size_t)(T_N + (T_N >> 4)) * sizeof(float2);    // 139264 B (fft_x)
  const size_t lds_l = (size_t)(8192 + (8192 >> 4)) * sizeof(float2);  // 69632 B (a)
  const size_t lds_s = (size_t)(4096 + (4096 >> 4)) * sizeof(float2);  // 34816 B (b)
  const size_t lds_x = (size_t)(2048 + (2048 >> 4)) * sizeof(float2);  // 17408 B (c)

  (void)hipFuncSetAttribute((const void*)k_fft_x, hipFuncAttributeMaxDynamicSharedMemorySize, (int)lds_h);
  (void)hipFuncSetAttribute((const void*)k_o1a,   hipFuncAttributeMaxDynamicSharedMemorySize, (int)lds_l);
  (void)hipFuncSetAttribute((const void*)k_o1b,   hipFuncAttributeMaxDynamicSharedMemorySize, (int)lds_s);
  (void)hipFuncSetAttribute((const void*)k_o1c,   hipFuncAttributeMaxDynamicSharedMemorySize, (int)lds_x);
  (void)hipFuncSetAttribute((const void*)k_o2a,   hipFuncAttributeMaxDynamicSharedMemorySize, (int)lds_l);
  (void)hipFuncSetAttribute((const void*)k_o2b,   hipFuncAttributeMaxDynamicSharedMemorySize, (int)lds_s);
  (void)hipFuncSetAttribute((const void*)k_o2c,   hipFuncAttributeMaxDynamicSharedMemorySize, (int)lds_x);

  hipLaunchKernelGGL(k_fft_x, dim3(B_SZ),      dim3(NT),  lds_h, stream, x, phi, xh, out);
  hipLaunchKernelGGL(k_o1a,   dim3(B_SZ * 8),  dim3(NT),  lds_l, stream, xh, psi1, phi, u1h, out);
  hipLaunchKernelGGL(k_o1b,   dim3(B_SZ * 8),  dim3(NTS), lds_s, stream, xh, psi1, phi, u1h, out);
  hipLaunchKernelGGL(k_o1c,   dim3(B_SZ * 20), dim3(NTX), lds_x, stream, xh, psi1, phi, u1h, out);
  hipLaunchKernelGGL(k_o2a,   dim3(B_SZ * 8),  dim3(NT),  lds_l, stream, u1h, psi2, phi, out);
  hipLaunchKernelGGL(k_o2b,   dim3(B_SZ * 40), dim3(NTS), lds_s, stream, u1h, psi2, phi, out);
  hipLaunchKernelGGL(k_o2c,   dim3(B_SZ * 78), dim3(NTX), lds_x, stream, u1h, psi2, phi, out);
}

// Round 17
// 184.317 us; speedup vs baseline: 1.1017x; 1.1017x over previous
//
#include <hip/hip_runtime.h>
#include <math.h>

// Wavelet scattering, T=16384.  R17 = R15 structure (5 launches, 512/256-thr
// blocks) + R16's j2=2/q0 class dropped to N'=4096 (merged into o2b as an
// existing LOGN=12 instantiation; o2a is j2=1-only).  R16's 7-launch /
// 128-thread variant regressed: launch-gap cost > barrier-domain win.

#define T_N   16384
#define NT    512
#define NTS   256
#define B_SZ  16
#define N1    64
#define NPAIR 224
#define FOLD_F 256
#define USTRIDE 8208
#define INV_N (1.0f/16384.0f)
#define TWO_PI 6.283185307179586f

typedef float v2f __attribute__((ext_vector_type(2)));

__device__ __forceinline__ int pad(int i) { return i + (i >> 4); }

__device__ __forceinline__ v2f cmulw(v2f a, v2f w){
  v2f n; n.x = -a.y; n.y = a.x;
  return w.x * a + w.y * n;
}
__device__ __forceinline__ constexpr int br4(int x){
  return ((x&1)<<3)|((x&2)<<1)|((x&4)>>1)|((x&8)>>3);
}
template<int LB>
__device__ __forceinline__ constexpr int brN(int x){
  int r=0;
  for(int i=0;i<LB;++i){ r=(r<<1)|((x>>i)&1); }
  return r;
}
__device__ __forceinline__ int rev4_14(int p){
  unsigned r = __brev((unsigned)p) >> 18;
  return (int)(((r & 0x2AAAu) >> 1) | ((r & 0x1555u) << 1));
}

// tw[r] = w^r via depth-4 product tree.
__device__ __forceinline__ void twiddle_tree(v2f w, v2f* tw){
  tw[0].x = 1.f; tw[0].y = 0.f;
  tw[1] = w;
  tw[2] = cmulw(w, w);
  tw[4] = cmulw(tw[2], tw[2]);
  tw[8] = cmulw(tw[4], tw[4]);
  tw[3] = cmulw(tw[2], w);
  tw[5] = cmulw(tw[4], w);
  tw[6] = cmulw(tw[4], tw[2]);
  tw[7] = cmulw(tw[4], tw[3]);
  tw[9]  = cmulw(tw[8], w);
  tw[10] = cmulw(tw[8], tw[2]);
  tw[11] = cmulw(tw[8], tw[3]);
  tw[12] = cmulw(tw[8], tw[4]);
  tw[13] = cmulw(tw[8], tw[5]);
  tw[14] = cmulw(tw[8], tw[6]);
  tw[15] = cmulw(tw[8], tw[7]);
}

// Generic fully-unrolled DFT of size 2^LOGNN (<=16); y[r] lands at a[brN(r)].
template<int SGN, int LOGNN>
__device__ __forceinline__ void dft_reg(v2f* a){
  constexpr int NN = 1<<LOGNN;
  static constexpr float C16[16] = {
    1.f, 0.98078528f, 0.92387953f, 0.83146961f, 0.70710678f, 0.55557023f,
    0.38268343f, 0.19509032f, 0.f, -0.19509032f, -0.38268343f, -0.55557023f,
    -0.70710678f, -0.83146961f, -0.92387953f, -0.98078528f };
  static constexpr float S16[16] = {
    0.f, 0.19509032f, 0.38268343f, 0.55557023f, 0.70710678f, 0.83146961f,
    0.92387953f, 0.98078528f, 1.f, 0.98078528f, 0.92387953f, 0.83146961f,
    0.70710678f, 0.55557023f, 0.38268343f, 0.19509032f };
#pragma unroll
  for (int m = NN/2; m >= 1; m >>= 1) {
#pragma unroll
    for (int base = 0; base < NN; base += 2*m) {
#pragma unroll
      for (int j = 0; j < m; ++j) {
        v2f u = a[base+j], v = a[base+j+m];
        a[base+j] = u + v;
        v2f w = u - v;
        const int ti = (j*16)/m;
        v2f tw; tw.x = C16[ti]; tw.y = (float)SGN * S16[ti];
        a[base+j+m] = cmulw(w, tw);
      }
    }
  }
}
template<int SGN>
__device__ __forceinline__ void dft16(v2f* a){ dft_reg<SGN,4>(a); }

// Full DIF super-stage radix-16 at stride M.
template<int SGN, int M, int LOGM>
__device__ __forceinline__ void super_dif16(v2f* d, int g)
{
  const int j = g & (M-1);
  const int base = ((g >> LOGM) << (LOGM+4)) | j;
  v2f* dp = d + pad(base);
  v2f a[16];
#pragma unroll
  for (int k = 0; k < 16; ++k) a[k] = dp[k*M + ((k*M)>>4)];
  dft16<SGN>(a);
  float sj, cj;
  __sincosf((float)SGN * (TWO_PI / (16.f*(float)M)) * (float)j, &sj, &cj);
  v2f w; w.x = cj; w.y = sj;
  v2f tw[16];
  twiddle_tree(w, tw);
  dp[0] = a[0];
#pragma unroll
  for (int r = 1; r < 16; ++r)
    dp[r*M + ((r*M)>>4)] = cmulw(a[br4(r)], tw[r]);
}

// SPARSE DIF super-stage: only taps [0,8) possibly nonzero (rest zeros).
template<int SGN, int M, int LOGM>
__device__ __forceinline__ void super_dif16_sp8(v2f* d, int g)
{
  static constexpr float CW[16] = { 1.f, 0.92387953f, 0.70710678f, 0.38268343f,
    0.f, -0.38268343f, -0.70710678f, -0.92387953f, -1.f, -0.92387953f,
    -0.70710678f, -0.38268343f, 0.f, 0.38268343f, 0.70710678f, 0.92387953f };
  static constexpr float SW[16] = { 0.f, 0.38268343f, 0.70710678f, 0.92387953f,
    1.f, 0.92387953f, 0.70710678f, 0.38268343f, 0.f, -0.38268343f,
    -0.70710678f, -0.92387953f, -1.f, -0.92387953f, -0.70710678f, -0.38268343f };
  const int j = g & (M-1);
  const int base = ((g >> LOGM) << (LOGM+4)) | j;
  v2f* dp = d + pad(base);
  v2f a[8];
#pragma unroll
  for (int m = 0; m < 8; ++m) a[m] = dp[m*M + ((m*M)>>4)];
  v2f y[16];
#pragma unroll
  for (int r0 = 0; r0 < 2; ++r0) {
    v2f z[8];
    z[0] = a[0];
#pragma unroll
    for (int m = 1; m < 8; ++m) {
      v2f w; w.x = CW[(m*r0)&15]; w.y = (float)SGN*SW[(m*r0)&15];
      z[m] = cmulw(a[m], w);
    }
    v2f E[4], O[4];
    {
      v2f e0=z[0]+z[4], e1=z[0]-z[4], o0=z[2]+z[6], o1=z[2]-z[6];
      v2f io; io.x=-(float)SGN*o1.y; io.y=(float)SGN*o1.x;
      E[0]=e0+o0; E[1]=e1+io; E[2]=e0-o0; E[3]=e1-io;
    }
    {
      v2f e0=z[1]+z[5], e1=z[1]-z[5], o0=z[3]+z[7], o1=z[3]-z[7];
      v2f io; io.x=-(float)SGN*o1.y; io.y=(float)SGN*o1.x;
      O[0]=e0+o0; O[1]=e1+io; O[2]=e0-o0; O[3]=e1-io;
    }
    constexpr float RT = 0.70710678f;
#pragma unroll
    for (int r1 = 0; r1 < 4; ++r1) {
      v2f w8;
      if (r1 == 0)      { w8.x = 1.f;  w8.y = 0.f; }
      else if (r1 == 1) { w8.x = RT;   w8.y = (float)SGN*RT; }
      else if (r1 == 2) { w8.x = 0.f;  w8.y = (float)SGN; }
      else              { w8.x = -RT;  w8.y = (float)SGN*RT; }
      v2f t = cmulw(O[r1], w8);
      y[2*r1 + r0]     = E[r1] + t;
      y[2*r1 + r0 + 8] = E[r1] - t;
    }
  }
  float sj, cj;
  __sincosf((float)SGN * (TWO_PI / (16.f*(float)M)) * (float)j, &sj, &cj);
  v2f w; w.x = cj; w.y = sj;
  v2f tw[16];
  twiddle_tree(w, tw);
  dp[0] = y[0];
#pragma unroll
  for (int r = 1; r < 16; ++r)
    dp[r*M + ((r*M)>>4)] = cmulw(y[r], tw[r]);
}

// Full DIT super-stage radix-16 at stride M.
template<int SGN, int M, int LOGM>
__device__ __forceinline__ void super_dit16(v2f* d, int g)
{
  const int j = g & (M-1);
  const int base = ((g >> LOGM) << (LOGM+4)) | j;
  v2f* dp = d + pad(base);
  float sj, cj;
  __sincosf((float)SGN * (TWO_PI / (16.f*(float)M)) * (float)j, &sj, &cj);
  v2f w; w.x = cj; w.y = sj;
  v2f tw[16];
  twiddle_tree(w, tw);
  v2f a[16];
  a[0] = dp[0];
#pragma unroll
  for (int k = 1; k < 16; ++k)
    a[k] = cmulw(dp[k*M + ((k*M)>>4)], tw[k]);
  dft16<SGN>(a);
#pragma unroll
  for (int r = 0; r < 16; ++r) dp[r*M + ((r*M)>>4)] = a[br4(r)];
}

// Generic output-pruned final DIT16 at M1 = 2^LOGM1: outputs r < RMAX.
template<int SGN, int LOGM1, int RMAX, bool JLIM>
__device__ __forceinline__ void final_prune(v2f* ds, int t)
{
  static constexpr float CW[16] = { 1.f, 0.92387953f, 0.70710678f, 0.38268343f,
    0.f, -0.38268343f, -0.70710678f, -0.92387953f, -1.f, -0.92387953f,
    -0.70710678f, -0.38268343f, 0.f, 0.38268343f, 0.70710678f, 0.92387953f };
  static constexpr float SW[16] = { 0.f, 0.38268343f, 0.70710678f, 0.92387953f,
    1.f, 0.92387953f, 0.70710678f, 0.38268343f, 0.f, -0.38268343f,
    -0.70710678f, -0.92387953f, -1.f, -0.92387953f, -0.70710678f, -0.38268343f };
  constexpr int M1 = 1<<LOGM1;
  const int j = t;
  if (JLIM && j >= 256) return;
  v2f* dp = ds + j + (j>>4);
  float sj, cj;
  __sincosf((float)SGN * (TWO_PI / (16.f*(float)M1)) * (float)j, &sj, &cj);
  v2f w; w.x = cj; w.y = sj;
  v2f tw[16];
  twiddle_tree(w, tw);
  v2f b[16];
  b[0] = dp[0];
#pragma unroll
  for (int k = 1; k < 16; ++k)
    b[k] = cmulw(dp[k*M1 + ((k*M1)>>4)], tw[k]);
#pragma unroll
  for (int r = 0; r < RMAX; ++r) {
    v2f acc = b[0];
#pragma unroll
    for (int k = 1; k < 16; ++k) {
      v2f wc; wc.x = CW[(r*k)&15]; wc.y = (float)SGN*SW[(r*k)&15];
      acc += cmulw(b[k], wc);
    }
    dp[r*M1 + ((r*M1)>>4)] = acc;
  }
}

// DIF chain descending (barrier after each stage).
template<int SGN, int LOGM>
__device__ __forceinline__ void dif_chain(v2f* ds, int t){
  super_dif16<SGN, (1<<LOGM), LOGM>(ds, t);
  __syncthreads();
  if constexpr (LOGM > 4) dif_chain<SGN, LOGM-4>(ds, t);
}
// DIT chain ascending up to (excluding) LOGTOP.
template<int SGN, int LOGM, int LOGTOP>
__device__ __forceinline__ void dit_chain(v2f* ds, int t){
  super_dit16<SGN, (1<<LOGM), LOGM>(ds, t);
  __syncthreads();
  if constexpr (LOGM + 4 < LOGTOP) dit_chain<SGN, LOGM+4, LOGTOP>(ds, t);
}

// Generic mid: per contiguous-16 (thread t): inverse DFT_MM -> |.|/T -> fwd DFT_MM.
template<int LOGMM>
__device__ __forceinline__ void mid_generic(v2f* ds, int t)
{
  constexpr int MM = 1<<LOGMM;
  v2f* dp = ds + 17*t;
#pragma unroll
  for (int q = 0; q < 16/MM; ++q) {
    v2f a[MM];
#pragma unroll
    for (int i = 0; i < MM; ++i) a[i] = dp[q*MM+i];
    dft_reg<+1,LOGMM>(a);
    v2f m[MM];
#pragma unroll
    for (int r = 0; r < MM; ++r) {
      v2f y = a[brN<LOGMM>(r)];
      m[r].x = INV_N * sqrtf(y.x*y.x + y.y*y.y);
      m[r].y = 0.f;
    }
    dft_reg<-1,LOGMM>(m);
#pragma unroll
    for (int k = 0; k < MM; ++k) dp[q*MM+k] = m[brN<LOGMM>(k)];
  }
}

// Generic decimated pipeline body, LOGN in {9..13}.  K1ST = 16 (full) or 8.
template<int LOGN, int RMAX, bool JL, int K1ST>
__device__ __forceinline__ void o2_body(v2f* ds, int t)
{
  constexpr int LOGM1 = LOGN-4;
  if constexpr (K1ST == 16) super_dif16<+1, (1<<LOGM1), LOGM1>(ds, t);
  else                      super_dif16_sp8<+1, (1<<LOGM1), LOGM1>(ds, t);
  __syncthreads();
  dif_chain<+1, LOGM1-4>(ds, t);
  constexpr int LOGMM = ((LOGM1-5)%4)+1;
  mid_generic<LOGMM>(ds, t);
  __syncthreads();
  dit_chain<-1, LOGMM, LOGM1>(ds, t);
  final_prune<-1, LOGM1, RMAX, JL>(ds, t);
  __syncthreads();
}

// Generic fold: SEGT = 64*PERK threads, scale applied at write.
template<int PERK>
__device__ __forceinline__ void fold_generic(const v2f* ds, const float* __restrict__ phi,
                                             float* outp, int t, float scale)
{
  const int k = t / PERK, g = t % PERK;
  float sv, cv, ss, cs;
  __sincosf((TWO_PI/64.f) * (float)((g*k) & 63), &sv, &cv);
  __sincosf((TWO_PI/64.f) * (float)((PERK*k) & 63), &ss, &cs);
  float acc = 0.f;
#pragma unroll
  for (int m = 0; m < 256/PERK; ++m) {
    const int f = g + PERK*m;
    v2f u = ds[f + (f>>4)];
    float wgt = phi[f] * ((f == 0) ? 1.f : 2.f);
    acc += wgt * (u.x*cv - u.y*sv);
    float nc = cv*cs - sv*ss, ns = cv*ss + sv*cs;
    cv = nc; sv = ns;
  }
#pragma unroll
  for (int o = 1; o < PERK; o <<= 1) acc += __shfl_xor(acc, o);
  if (g == 0) outp[k] = acc * scale;
}

// Fold for N'=512 pipelines (SEGT=32): exact 256->64 pre-fold, then 64-pt DFT.
// Scratch in free LDS slots [384, 448) of the pipeline.
__device__ __forceinline__ void fold32(v2f* ds, const float* __restrict__ phi,
                                       float* outp, int t, float scale, bool valid)
{
#pragma unroll
  for (int h = 0; h < 2; ++h) {
    const int g = t + 32*h;
    v2f acc; acc.x = 0.f; acc.y = 0.f;
#pragma unroll
    for (int m = 0; m < 4; ++m) {
      const int f = g + 64*m;
      v2f u = ds[f + (f>>4)];
      float wgt = phi[f] * ((f == 0) ? 1.f : 2.f);
      acc += wgt * u;
    }
    const int s = 384 + g;
    ds[s + (s>>4)] = acc;
  }
  __syncthreads();
  if (valid) {
#pragma unroll
    for (int h = 0; h < 2; ++h) {
      const int k = t + 32*h;
      float ss, cs;
      __sincosf((TWO_PI/64.f) * (float)k, &ss, &cs);
      float cv = 1.f, sv = 0.f, acc = 0.f;
      for (int g = 0; g < 64; ++g) {
        const int s = 384 + g;
        v2f V = ds[s + (s>>4)];
        acc += V.x*cv - V.y*sv;
        float nc = cv*cs - sv*ss, ns = cv*ss + sv*cs;
        cv = nc; sv = ns;
      }
      outp[k] = acc * scale;
    }
  }
}

// Reference pair index (j1-major, valid j2 > j1/8).
__device__ __forceinline__ int pair_index(int j1, int j2)
{
  const int q = j1 >> 3;
  return 8*(7*q - (q*(q-1))/2) + (j1 & 7)*(7 - q) + (j2 - q - 1);
}

// psi2 band widths W(j2) = ceil(4.5 * 5734.4 * 2^-j2)
__device__ __constant__ int WTAB[8]  = {16384, 12903, 6452, 3226, 1613, 807, 404, 202};
// U1h truncation per j1-octave q: tb = ~0.8*c(8q) = 6.3 sigma_env.
__device__ __constant__ int TBTAB[8] = {4600, 2300, 1152, 576, 292, 148, 76, 40};

// ---- radix-4 float2 path for k_fft_x ----
__device__ __forceinline__ float2 f2add(float2 a, float2 b){ return make_float2(a.x+b.x, a.y+b.y); }
__device__ __forceinline__ float2 f2sub(float2 a, float2 b){ return make_float2(a.x-b.x, a.y-b.y); }
__device__ __forceinline__ float2 cmul_cs(float2 a, float c, float s){
  return make_float2(a.x*c - a.y*s, a.x*s + a.y*c);
}
__device__ void dif_sweep(float2* d, int tid, float sgn, int mb_hi, int mb_lo)
{
  const float ang = sgn * (TWO_PI / (float)T_N);
  for (int mbits = mb_hi; mbits >= mb_lo; mbits -= 2) {
    const int M = 1 << mbits;
#pragma unroll 8
    for (int v = tid; v < T_N/4; v += NT) {
      const int j = v & (M-1);
      const int base = ((v >> mbits) << (mbits+2)) | j;
      const int i0 = pad(base), i1 = pad(base+M), i2 = pad(base+2*M), i3 = pad(base+3*M);
      float2 a0=d[i0], a1=d[i1], a2=d[i2], a3=d[i3];
      float2 t0=f2add(a0,a2), t1=f2sub(a0,a2), t2=f2add(a1,a3), t3=f2sub(a1,a3);
      float2 y0=f2add(t0,t2), y2=f2sub(t0,t2);
      float2 y1=make_float2(t1.x - sgn*t3.y, t1.y + sgn*t3.x);
      float2 y3=make_float2(t1.x + sgn*t3.y, t1.y - sgn*t3.x);
      float s1,c1;
      __sincosf(ang * (float)(j << (12-mbits)), &s1, &c1);
      float c2=c1*c1-s1*s1, s2=2.f*c1*s1;
      float c3=c1*c2-s1*s2, s3=c1*s2+s1*c2;
      d[i0]=y0;
      d[i1]=cmul_cs(y1,c1,s1);
      d[i2]=cmul_cs(y2,c2,s2);
      d[i3]=cmul_cs(y3,c3,s3);
    }
    __syncthreads();
  }
}
__device__ void fold_store8(const float2* d, const float* __restrict__ phi, float* outp, int tid)
{
  const int k = tid >> 3, g = tid & 7;
  float acc = 0.f;
  for (int f = g; f < FOLD_F; f += 8) {
    float2 u = d[pad(f)];
    float w = phi[f] * ((f == 0) ? 1.f : 2.f);
    float sv, cv;
    __sincosf((TWO_PI/64.f) * (float)((f*k) & 63), &sv, &cv);
    acc += w * (u.x*cv - u.y*sv);
  }
  acc += __shfl_xor(acc, 1);
  acc += __shfl_xor(acc, 2);
  acc += __shfl_xor(acc, 4);
  if (g == 0) outp[k] = acc * INV_N;
}

// K1: xh = FFT(x) + S0 fold.
__global__ void __launch_bounds__(NT) k_fft_x(const float* __restrict__ x, const float* __restrict__ phi,
                                              float2* __restrict__ xh, float* __restrict__ out)
{
  extern __shared__ char smem[];
  float2* d = (float2*)smem;
  const int tid = threadIdx.x;
  const int b = blockIdx.x;
  const float* xr = x + b * T_N;
  for (int i = tid; i < T_N; i += NT) d[pad(i)] = make_float2(xr[i], 0.f);
  __syncthreads();
  dif_sweep(d, tid, -1.f, 12, 0);
  for (int p = tid; p < T_N; p += NT) {
    int r = rev4_14(p);
    if (p < r) { int ip = pad(p), ir = pad(r); float2 t = d[ip]; d[ip] = d[ir]; d[ir] = t; }
  }
  __syncthreads();
  float2* xrow = xh + (size_t)b * T_N;
  for (int i = tid; i < T_N; i += NT) xrow[i] = d[pad(i)];
  fold_store8(d, phi, out + b * 64, tid);
}

// Decimated order-1 body: demodulated band [lo,hi) at slots [0,W).
template<int LOGN>
__device__ __forceinline__ void o1_dec_body(v2f* sm, int sub, int t, int j1, int b,
    const float2* __restrict__ xh, const float* __restrict__ psi1,
    const float* __restrict__ phi, float2* __restrict__ u1h, float* __restrict__ out)
{
  constexpr int N = 1<<LOGN, SEGT = N/16;
  v2f* ds = sm + sub*N + ((sub*N)>>4);
  const float c = 5734.4f * exp2f(-0.125f*(float)j1);
  const int lo = max(0, (int)(0.36f*c));
  const int hi = min(T_N, (int)(1.64f*c)+2);
  const int W = hi - lo;
  const float2* xrow = xh + (size_t)b * T_N;
  const float* prow = psi1 + j1 * T_N;
#pragma unroll
  for (int s = 0; s < 16; ++s) {
    int f = t + s*SEGT;
    v2f z; z.x = 0.f; z.y = 0.f;
    if (f < W) { float2 xv = xrow[lo+f]; float p = prow[lo+f]; z.x = xv.x*p; z.y = xv.y*p; }
    ds[f + (f>>4)] = z;
  }
  __syncthreads();
  constexpr int RM = (LOGN == 9) ? 10 : 9;
  o2_body<LOGN, RM, false, 16>(ds, t);
  const int tb = TBTAB[(j1>>3) & 7];
  const float R = (float)(T_N >> LOGN);
  float2* urow = u1h + (size_t)(b*N1 + j1) * USTRIDE;
  for (int i = t; i < tb; i += SEGT) {
    v2f u = ds[i + (i>>4)];
    urow[i] = make_float2(R*u.x, R*u.y);
  }
  float* outp = out + 1024 + (size_t)(b*N1 + j1)*64;
  if constexpr (SEGT >= 64) fold_generic<SEGT/64>(ds, phi, outp, t, 1.f/(float)N);
  else                      fold32(ds, phi, outp, t, 1.f/(float)N, true);
}

// K2a (order-1, N'=8192 only): j1 0-7, 1 pipeline/block, 512 thr. 128 blocks.
__global__ void __launch_bounds__(NT, 4) k_o1a(const float2* __restrict__ xh, const float* __restrict__ psi1,
                                               const float* __restrict__ phi, float2* __restrict__ u1h,
                                               float* __restrict__ out)
{
  extern __shared__ char smem[];
  o1_dec_body<13>((v2f*)smem, 0, threadIdx.x, blockIdx.x / B_SZ, blockIdx.x % B_SZ,
                  xh, psi1, phi, u1h, out);
}

// K2b (order-1, N' <= 4096): 256-thread / 34.8KB blocks, 4 blocks/CU.
// 18 groups per batch: grp 0-7: q=1 4096 (1 ppl/blk) | 8-11: q=2 2048 (2)
// | 12-13: q=3 1024 (4) | 14-17: q>=4 512 (8).
__global__ void __launch_bounds__(NTS, 4) k_o1b(const float2* __restrict__ xh, const float* __restrict__ psi1,
                                                const float* __restrict__ phi, float2* __restrict__ u1h,
                                                float* __restrict__ out)
{
  extern __shared__ char smem[];
  v2f* sm = (v2f*)smem;
  const int grp = blockIdx.x / B_SZ, b = blockIdx.x % B_SZ;
  const int tid = threadIdx.x;
  if (grp < 8) {
    o1_dec_body<12>(sm, 0, tid, 8 + grp, b, xh, psi1, phi, u1h, out);
  } else if (grp < 12) {
    const int sub = tid >> 7;
    o1_dec_body<11>(sm, sub, tid & 127, 16 + (grp-8)*2 + sub, b, xh, psi1, phi, u1h, out);
  } else if (grp < 14) {
    const int sub = tid >> 6;
    o1_dec_body<10>(sm, sub, tid & 63, 24 + (grp-12)*4 + sub, b, xh, psi1, phi, u1h, out);
  } else {
    const int sub = tid >> 5;
    o1_dec_body<9>(sm, sub, tid & 31, 32 + (grp-14)*8 + sub, b, xh, psi1, phi, u1h, out);
  }
}

// Decimated order-2 body (S2 fold only).  Input support min(W, tb, N) — input
// past N is >= 5.6 sigma_env of the U1 envelope for affected classes.
template<int LOGN, int K1ST>
__device__ __forceinline__ void o2_cls_body(v2f* sm, int sub, int t, int b, int j1, int j2, bool valid,
    const float2* __restrict__ u1h, const float* __restrict__ psi2,
    const float* __restrict__ phi, float* __restrict__ out)
{
  constexpr int N = 1<<LOGN, SEGT = N/16;
  v2f* ds = sm + sub*N + ((sub*N)>>4);
  const int W  = WTAB[j2 & 7];
  const int tb = TBTAB[(j1 >> 3) & 7];
  const int lim = min(min(W, tb), N);
  const float2* urow = u1h + (size_t)(b * N1 + j1) * USTRIDE;
  const float* prow = psi2 + j2 * T_N;
#pragma unroll
  for (int s = 0; s < 16; ++s) {
    int f = t + s*SEGT;
    v2f z; z.x = 0.f; z.y = 0.f;
    if (valid && f < lim) { float2 u = urow[f]; float ps = prow[f]; z.x = u.x*ps; z.y = u.y*ps; }
    ds[f + (f>>4)] = z;
  }
  __syncthreads();
  constexpr int RM = ((1<<(LOGN-4)) >= 256) ? 1 : (256 >> (LOGN-4));
  constexpr bool JL = ((1<<(LOGN-4)) > 256);
  o2_body<LOGN, RM, JL, K1ST>(ds, t);
  float* outp = out + 66560 + (size_t)(b * NPAIR + pair_index(j1, j2)) * 64;
  if constexpr (SEGT >= 64) { if (valid) fold_generic<SEGT/64>(ds, phi, outp, t, 1.f/(float)N); }
  else                      fold32(ds, phi, outp, t, 1.f/(float)N, valid);
}

// K3a (order-2, j2=1 @ N'=8192): j1 0-7, 512 thr, sp8 first stage. 128 blocks.
__global__ void __launch_bounds__(NT, 4) k_o2a(const float2* __restrict__ u1h, const float* __restrict__ psi2,
                                               const float* __restrict__ phi, float* __restrict__ out)
{
  extern __shared__ char smem[];
  o2_cls_body<13,8>((v2f*)smem, 0, threadIdx.x, blockIdx.x % B_SZ, blockIdx.x / B_SZ, 1, true,
                    u1h, psi2, phi, out);
}

// K3b (order-2, N' <= 4096): 256-thread / 34.8KB blocks, 4 blocks/CU.
// 79 groups per batch, heavy-first:
// grp 0-7:  j2=2 q=0 4096 (1/blk, lim clamped) | 8-15: j2=2 q=1 4096 (1/blk)
// | 16-39: j2=3 4096 (1/blk, j1=grp-16) | 40-55: j2=4 2048 (2/blk)
// | 56-65: j2=5 1024 (4/blk) | 66-71: j2=6 512 (8/blk)
// | 72-78: j2=7 512 (8/blk, j1 0-55).
__global__ void __launch_bounds__(NTS, 4) k_o2b(const float2* __restrict__ u1h, const float* __restrict__ psi2,
                                                const float* __restrict__ phi, float* __restrict__ out)
{
  extern __shared__ char smem[];
  v2f* sm = (v2f*)smem;
  const int grp = blockIdx.x / B_SZ, b = blockIdx.x % B_SZ;
  const int tid = threadIdx.x;
  if (grp < 16) {
    o2_cls_body<12,16>(sm, 0, tid, b, grp, 2, true, u1h, psi2, phi, out);
  } else if (grp < 40) {
    o2_cls_body<12,16>(sm, 0, tid, b, grp - 16, 3, true, u1h, psi2, phi, out);
  } else if (grp < 56) {
    const int sub = tid >> 7;
    o2_cls_body<11,16>(sm, sub, tid & 127, b, (grp-40)*2 + sub, 4, true, u1h, psi2, phi, out);
  } else if (grp < 66) {
    const int sub = tid >> 6;
    o2_cls_body<10,16>(sm, sub, tid & 63, b, (grp-56)*4 + sub, 5, true, u1h, psi2, phi, out);
  } else if (grp < 72) {
    const int sub = tid >> 5;
    o2_cls_body<9,16>(sm, sub, tid & 31, b, (grp-66)*8 + sub, 6, true, u1h, psi2, phi, out);
  } else {
    const int sub = tid >> 5;
    o2_cls_body<9,8>(sm, sub, tid & 31, b, (grp-72)*8 + sub, 7, true, u1h, psi2, phi, out);
  }
}

extern "C" void kernel_launch(void* const* d_in, const int* in_sizes, int n_in,
                              void* d_out, int out_size, void* d_ws, size_t ws_size,
                              hipStream_t stream)
{
  const float* x    = (const float*)d_in[0];
  const float* psi1 = (const float*)d_in[1];
  const float* psi2 = (const float*)d_in[2];
  const float* phi  = (const float*)d_in[3];
  float* out = (float*)d_out;

  float2* xh  = (float2*)d_ws;
  float2* u1h = xh + (size_t)B_SZ * T_N;

  const size_t lds_h = (size_t)(T_N + (T_N >> 4)) * sizeof(float2);    // 139264 B (fft_x)
  const size_t lds_l = (size_t)(8192 + (8192 >> 4)) * sizeof(float2);  // 69632 B (o1a/o2a)
  const size_t lds_s = (size_t)(4096 + (4096 >> 4)) * sizeof(float2);  // 34816 B (o1b/o2b)

  (void)hipFuncSetAttribute((const void*)k_fft_x, hipFuncAttributeMaxDynamicSharedMemorySize, (int)lds_h);
  (void)hipFuncSetAttribute((const void*)k_o1a,   hipFuncAttributeMaxDynamicSharedMemorySize, (int)lds_l);
  (void)hipFuncSetAttribute((const void*)k_o1b,   hipFuncAttributeMaxDynamicSharedMemorySize, (int)lds_s);
  (void)hipFuncSetAttribute((const void*)k_o2a,   hipFuncAttributeMaxDynamicSharedMemorySize, (int)lds_l);
  (void)hipFuncSetAttribute((const void*)k_o2b,   hipFuncAttributeMaxDynamicSharedMemorySize, (int)lds_s);

  hipLaunchKernelGGL(k_fft_x, dim3(B_SZ),      dim3(NT),  lds_h, stream, x, phi, xh, out);
  hipLaunchKernelGGL(k_o1a,   dim3(B_SZ * 8),  dim3(NT),  lds_l, stream, xh, psi1, phi, u1h, out);
  hipLaunchKernelGGL(k_o1b,   dim3(B_SZ * 18), dim3(NTS), lds_s, stream, xh, psi1, phi, u1h, out);
  hipLaunchKernelGGL(k_o2a,   dim3(B_SZ * 8),  dim3(NT),  lds_l, stream, u1h, psi2, phi, out);
  hipLaunchKernelGGL(k_o2b,   dim3(B_SZ * 79), dim3(NTS), lds_s, stream, u1h, psi2, phi, out);
}

// Round 18
// 179.689 us; speedup vs baseline: 1.1301x; 1.0258x over previous
//
#include <hip/hip_runtime.h>
#include <math.h>

// Wavelet scattering, T=16384.  R18 = R17 with grid-shape rebalance:
// j2=2 classes (LOGN=12) moved from o2b into o2a as 2-pipelines-per-512-thr
// block (2x4352 = 8704 slots = exactly the 69.6KB block).  o2a: 256 blocks
// (half of its 512 co-residency slots, was 25%); o2b: 63 grp = 1008 blocks
// <= 1024 slots -> exactly one round (was 1264 -> straggler round).
// 5 launches: fft_x -> o1a(8192) -> o1b(<=4096) -> o2a(j2=1,2) -> o2b(j2>=3).

#define T_N   16384
#define NT    512
#define NTS   256
#define B_SZ  16
#define N1    64
#define NPAIR 224
#define FOLD_F 256
#define USTRIDE 8208
#define INV_N (1.0f/16384.0f)
#define TWO_PI 6.283185307179586f

typedef float v2f __attribute__((ext_vector_type(2)));

__device__ __forceinline__ int pad(int i) { return i + (i >> 4); }

__device__ __forceinline__ v2f cmulw(v2f a, v2f w){
  v2f n; n.x = -a.y; n.y = a.x;
  return w.x * a + w.y * n;
}
__device__ __forceinline__ constexpr int br4(int x){
  return ((x&1)<<3)|((x&2)<<1)|((x&4)>>1)|((x&8)>>3);
}
template<int LB>
__device__ __forceinline__ constexpr int brN(int x){
  int r=0;
  for(int i=0;i<LB;++i){ r=(r<<1)|((x>>i)&1); }
  return r;
}
__device__ __forceinline__ int rev4_14(int p){
  unsigned r = __brev((unsigned)p) >> 18;
  return (int)(((r & 0x2AAAu) >> 1) | ((r & 0x1555u) << 1));
}

// tw[r] = w^r via depth-4 product tree.
__device__ __forceinline__ void twiddle_tree(v2f w, v2f* tw){
  tw[0].x = 1.f; tw[0].y = 0.f;
  tw[1] = w;
  tw[2] = cmulw(w, w);
  tw[4] = cmulw(tw[2], tw[2]);
  tw[8] = cmulw(tw[4], tw[4]);
  tw[3] = cmulw(tw[2], w);
  tw[5] = cmulw(tw[4], w);
  tw[6] = cmulw(tw[4], tw[2]);
  tw[7] = cmulw(tw[4], tw[3]);
  tw[9]  = cmulw(tw[8], w);
  tw[10] = cmulw(tw[8], tw[2]);
  tw[11] = cmulw(tw[8], tw[3]);
  tw[12] = cmulw(tw[8], tw[4]);
  tw[13] = cmulw(tw[8], tw[5]);
  tw[14] = cmulw(tw[8], tw[6]);
  tw[15] = cmulw(tw[8], tw[7]);
}

// Generic fully-unrolled DFT of size 2^LOGNN (<=16); y[r] lands at a[brN(r)].
template<int SGN, int LOGNN>
__device__ __forceinline__ void dft_reg(v2f* a){
  constexpr int NN = 1<<LOGNN;
  static constexpr float C16[16] = {
    1.f, 0.98078528f, 0.92387953f, 0.83146961f, 0.70710678f, 0.55557023f,
    0.38268343f, 0.19509032f, 0.f, -0.19509032f, -0.38268343f, -0.55557023f,
    -0.70710678f, -0.83146961f, -0.92387953f, -0.98078528f };
  static constexpr float S16[16] = {
    0.f, 0.19509032f, 0.38268343f, 0.55557023f, 0.70710678f, 0.83146961f,
    0.92387953f, 0.98078528f, 1.f, 0.98078528f, 0.92387953f, 0.83146961f,
    0.70710678f, 0.55557023f, 0.38268343f, 0.19509032f };
#pragma unroll
  for (int m = NN/2; m >= 1; m >>= 1) {
#pragma unroll
    for (int base = 0; base < NN; base += 2*m) {
#pragma unroll
      for (int j = 0; j < m; ++j) {
        v2f u = a[base+j], v = a[base+j+m];
        a[base+j] = u + v;
        v2f w = u - v;
        const int ti = (j*16)/m;
        v2f tw; tw.x = C16[ti]; tw.y = (float)SGN * S16[ti];
        a[base+j+m] = cmulw(w, tw);
      }
    }
  }
}
template<int SGN>
__device__ __forceinline__ void dft16(v2f* a){ dft_reg<SGN,4>(a); }

// Full DIF super-stage radix-16 at stride M.
template<int SGN, int M, int LOGM>
__device__ __forceinline__ void super_dif16(v2f* d, int g)
{
  const int j = g & (M-1);
  const int base = ((g >> LOGM) << (LOGM+4)) | j;
  v2f* dp = d + pad(base);
  v2f a[16];
#pragma unroll
  for (int k = 0; k < 16; ++k) a[k] = dp[k*M + ((k*M)>>4)];
  dft16<SGN>(a);
  float sj, cj;
  __sincosf((float)SGN * (TWO_PI / (16.f*(float)M)) * (float)j, &sj, &cj);
  v2f w; w.x = cj; w.y = sj;
  v2f tw[16];
  twiddle_tree(w, tw);
  dp[0] = a[0];
#pragma unroll
  for (int r = 1; r < 16; ++r)
    dp[r*M + ((r*M)>>4)] = cmulw(a[br4(r)], tw[r]);
}

// SPARSE DIF super-stage: only taps [0,8) possibly nonzero (rest zeros).
template<int SGN, int M, int LOGM>
__device__ __forceinline__ void super_dif16_sp8(v2f* d, int g)
{
  static constexpr float CW[16] = { 1.f, 0.92387953f, 0.70710678f, 0.38268343f,
    0.f, -0.38268343f, -0.70710678f, -0.92387953f, -1.f, -0.92387953f,
    -0.70710678f, -0.38268343f, 0.f, 0.38268343f, 0.70710678f, 0.92387953f };
  static constexpr float SW[16] = { 0.f, 0.38268343f, 0.70710678f, 0.92387953f,
    1.f, 0.92387953f, 0.70710678f, 0.38268343f, 0.f, -0.38268343f,
    -0.70710678f, -0.92387953f, -1.f, -0.92387953f, -0.70710678f, -0.38268343f };
  const int j = g & (M-1);
  const int base = ((g >> LOGM) << (LOGM+4)) | j;
  v2f* dp = d + pad(base);
  v2f a[8];
#pragma unroll
  for (int m = 0; m < 8; ++m) a[m] = dp[m*M + ((m*M)>>4)];
  v2f y[16];
#pragma unroll
  for (int r0 = 0; r0 < 2; ++r0) {
    v2f z[8];
    z[0] = a[0];
#pragma unroll
    for (int m = 1; m < 8; ++m) {
      v2f w; w.x = CW[(m*r0)&15]; w.y = (float)SGN*SW[(m*r0)&15];
      z[m] = cmulw(a[m], w);
    }
    v2f E[4], O[4];
    {
      v2f e0=z[0]+z[4], e1=z[0]-z[4], o0=z[2]+z[6], o1=z[2]-z[6];
      v2f io; io.x=-(float)SGN*o1.y; io.y=(float)SGN*o1.x;
      E[0]=e0+o0; E[1]=e1+io; E[2]=e0-o0; E[3]=e1-io;
    }
    {
      v2f e0=z[1]+z[5], e1=z[1]-z[5], o0=z[3]+z[7], o1=z[3]-z[7];
      v2f io; io.x=-(float)SGN*o1.y; io.y=(float)SGN*o1.x;
      O[0]=e0+o0; O[1]=e1+io; O[2]=e0-o0; O[3]=e1-io;
    }
    constexpr float RT = 0.70710678f;
#pragma unroll
    for (int r1 = 0; r1 < 4; ++r1) {
      v2f w8;
      if (r1 == 0)      { w8.x = 1.f;  w8.y = 0.f; }
      else if (r1 == 1) { w8.x = RT;   w8.y = (float)SGN*RT; }
      else if (r1 == 2) { w8.x = 0.f;  w8.y = (float)SGN; }
      else              { w8.x = -RT;  w8.y = (float)SGN*RT; }
      v2f t = cmulw(O[r1], w8);
      y[2*r1 + r0]     = E[r1] + t;
      y[2*r1 + r0 + 8] = E[r1] - t;
    }
  }
  float sj, cj;
  __sincosf((float)SGN * (TWO_PI / (16.f*(float)M)) * (float)j, &sj, &cj);
  v2f w; w.x = cj; w.y = sj;
  v2f tw[16];
  twiddle_tree(w, tw);
  dp[0] = y[0];
#pragma unroll
  for (int r = 1; r < 16; ++r)
    dp[r*M + ((r*M)>>4)] = cmulw(y[r], tw[r]);
}

// Full DIT super-stage radix-16 at stride M.
template<int SGN, int M, int LOGM>
__device__ __forceinline__ void super_dit16(v2f* d, int g)
{
  const int j = g & (M-1);
  const int base = ((g >> LOGM) << (LOGM+4)) | j;
  v2f* dp = d + pad(base);
  float sj, cj;
  __sincosf((float)SGN * (TWO_PI / (16.f*(float)M)) * (float)j, &sj, &cj);
  v2f w; w.x = cj; w.y = sj;
  v2f tw[16];
  twiddle_tree(w, tw);
  v2f a[16];
  a[0] = dp[0];
#pragma unroll
  for (int k = 1; k < 16; ++k)
    a[k] = cmulw(dp[k*M + ((k*M)>>4)], tw[k]);
  dft16<SGN>(a);
#pragma unroll
  for (int r = 0; r < 16; ++r) dp[r*M + ((r*M)>>4)] = a[br4(r)];
}

// Generic output-pruned final DIT16 at M1 = 2^LOGM1: outputs r < RMAX.
template<int SGN, int LOGM1, int RMAX, bool JLIM>
__device__ __forceinline__ void final_prune(v2f* ds, int t)
{
  static constexpr float CW[16] = { 1.f, 0.92387953f, 0.70710678f, 0.38268343f,
    0.f, -0.38268343f, -0.70710678f, -0.92387953f, -1.f, -0.92387953f,
    -0.70710678f, -0.38268343f, 0.f, 0.38268343f, 0.70710678f, 0.92387953f };
  static constexpr float SW[16] = { 0.f, 0.38268343f, 0.70710678f, 0.92387953f,
    1.f, 0.92387953f, 0.70710678f, 0.38268343f, 0.f, -0.38268343f,
    -0.70710678f, -0.92387953f, -1.f, -0.92387953f, -0.70710678f, -0.38268343f };
  constexpr int M1 = 1<<LOGM1;
  const int j = t;
  if (JLIM && j >= 256) return;
  v2f* dp = ds + j + (j>>4);
  float sj, cj;
  __sincosf((float)SGN * (TWO_PI / (16.f*(float)M1)) * (float)j, &sj, &cj);
  v2f w; w.x = cj; w.y = sj;
  v2f tw[16];
  twiddle_tree(w, tw);
  v2f b[16];
  b[0] = dp[0];
#pragma unroll
  for (int k = 1; k < 16; ++k)
    b[k] = cmulw(dp[k*M1 + ((k*M1)>>4)], tw[k]);
#pragma unroll
  for (int r = 0; r < RMAX; ++r) {
    v2f acc = b[0];
#pragma unroll
    for (int k = 1; k < 16; ++k) {
      v2f wc; wc.x = CW[(r*k)&15]; wc.y = (float)SGN*SW[(r*k)&15];
      acc += cmulw(b[k], wc);
    }
    dp[r*M1 + ((r*M1)>>4)] = acc;
  }
}

// DIF chain descending (barrier after each stage).
template<int SGN, int LOGM>
__device__ __forceinline__ void dif_chain(v2f* ds, int t){
  super_dif16<SGN, (1<<LOGM), LOGM>(ds, t);
  __syncthreads();
  if constexpr (LOGM > 4) dif_chain<SGN, LOGM-4>(ds, t);
}
// DIT chain ascending up to (excluding) LOGTOP.
template<int SGN, int LOGM, int LOGTOP>
__device__ __forceinline__ void dit_chain(v2f* ds, int t){
  super_dit16<SGN, (1<<LOGM), LOGM>(ds, t);
  __syncthreads();
  if constexpr (LOGM + 4 < LOGTOP) dit_chain<SGN, LOGM+4, LOGTOP>(ds, t);
}

// Generic mid: per contiguous-16 (thread t): inverse DFT_MM -> |.|/T -> fwd DFT_MM.
template<int LOGMM>
__device__ __forceinline__ void mid_generic(v2f* ds, int t)
{
  constexpr int MM = 1<<LOGMM;
  v2f* dp = ds + 17*t;
#pragma unroll
  for (int q = 0; q < 16/MM; ++q) {
    v2f a[MM];
#pragma unroll
    for (int i = 0; i < MM; ++i) a[i] = dp[q*MM+i];
    dft_reg<+1,LOGMM>(a);
    v2f m[MM];
#pragma unroll
    for (int r = 0; r < MM; ++r) {
      v2f y = a[brN<LOGMM>(r)];
      m[r].x = INV_N * sqrtf(y.x*y.x + y.y*y.y);
      m[r].y = 0.f;
    }
    dft_reg<-1,LOGMM>(m);
#pragma unroll
    for (int k = 0; k < MM; ++k) dp[q*MM+k] = m[brN<LOGMM>(k)];
  }
}

// Generic decimated pipeline body, LOGN in {9..13}.  K1ST = 16 (full) or 8.
template<int LOGN, int RMAX, bool JL, int K1ST>
__device__ __forceinline__ void o2_body(v2f* ds, int t)
{
  constexpr int LOGM1 = LOGN-4;
  if constexpr (K1ST == 16) super_dif16<+1, (1<<LOGM1), LOGM1>(ds, t);
  else                      super_dif16_sp8<+1, (1<<LOGM1), LOGM1>(ds, t);
  __syncthreads();
  dif_chain<+1, LOGM1-4>(ds, t);
  constexpr int LOGMM = ((LOGM1-5)%4)+1;
  mid_generic<LOGMM>(ds, t);
  __syncthreads();
  dit_chain<-1, LOGMM, LOGM1>(ds, t);
  final_prune<-1, LOGM1, RMAX, JL>(ds, t);
  __syncthreads();
}

// Generic fold: SEGT = 64*PERK threads, scale applied at write.
template<int PERK>
__device__ __forceinline__ void fold_generic(const v2f* ds, const float* __restrict__ phi,
                                             float* outp, int t, float scale)
{
  const int k = t / PERK, g = t % PERK;
  float sv, cv, ss, cs;
  __sincosf((TWO_PI/64.f) * (float)((g*k) & 63), &sv, &cv);
  __sincosf((TWO_PI/64.f) * (float)((PERK*k) & 63), &ss, &cs);
  float acc = 0.f;
#pragma unroll
  for (int m = 0; m < 256/PERK; ++m) {
    const int f = g + PERK*m;
    v2f u = ds[f + (f>>4)];
    float wgt = phi[f] * ((f == 0) ? 1.f : 2.f);
    acc += wgt * (u.x*cv - u.y*sv);
    float nc = cv*cs - sv*ss, ns = cv*ss + sv*cs;
    cv = nc; sv = ns;
  }
#pragma unroll
  for (int o = 1; o < PERK; o <<= 1) acc += __shfl_xor(acc, o);
  if (g == 0) outp[k] = acc * scale;
}

// Fold for N'=512 pipelines (SEGT=32): exact 256->64 pre-fold, then 64-pt DFT.
// Scratch in free LDS slots [384, 448) of the pipeline.
__device__ __forceinline__ void fold32(v2f* ds, const float* __restrict__ phi,
                                       float* outp, int t, float scale, bool valid)
{
#pragma unroll
  for (int h = 0; h < 2; ++h) {
    const int g = t + 32*h;
    v2f acc; acc.x = 0.f; acc.y = 0.f;
#pragma unroll
    for (int m = 0; m < 4; ++m) {
      const int f = g + 64*m;
      v2f u = ds[f + (f>>4)];
      float wgt = phi[f] * ((f == 0) ? 1.f : 2.f);
      acc += wgt * u;
    }
    const int s = 384 + g;
    ds[s + (s>>4)] = acc;
  }
  __syncthreads();
  if (valid) {
#pragma unroll
    for (int h = 0; h < 2; ++h) {
      const int k = t + 32*h;
      float ss, cs;
      __sincosf((TWO_PI/64.f) * (float)k, &ss, &cs);
      float cv = 1.f, sv = 0.f, acc = 0.f;
      for (int g = 0; g < 64; ++g) {
        const int s = 384 + g;
        v2f V = ds[s + (s>>4)];
        acc += V.x*cv - V.y*sv;
        float nc = cv*cs - sv*ss, ns = cv*ss + sv*cs;
        cv = nc; sv = ns;
      }
      outp[k] = acc * scale;
    }
  }
}

// Reference pair index (j1-major, valid j2 > j1/8).
__device__ __forceinline__ int pair_index(int j1, int j2)
{
  const int q = j1 >> 3;
  return 8*(7*q - (q*(q-1))/2) + (j1 & 7)*(7 - q) + (j2 - q - 1);
}

// psi2 band widths W(j2) = ceil(4.5 * 5734.4 * 2^-j2)
__device__ __constant__ int WTAB[8]  = {16384, 12903, 6452, 3226, 1613, 807, 404, 202};
// U1h truncation per j1-octave q: tb = ~0.8*c(8q) = 6.3 sigma_env.
__device__ __constant__ int TBTAB[8] = {4600, 2300, 1152, 576, 292, 148, 76, 40};

// ---- radix-4 float2 path for k_fft_x ----
__device__ __forceinline__ float2 f2add(float2 a, float2 b){ return make_float2(a.x+b.x, a.y+b.y); }
__device__ __forceinline__ float2 f2sub(float2 a, float2 b){ return make_float2(a.x-b.x, a.y-b.y); }
__device__ __forceinline__ float2 cmul_cs(float2 a, float c, float s){
  return make_float2(a.x*c - a.y*s, a.x*s + a.y*c);
}
__device__ void dif_sweep(float2* d, int tid, float sgn, int mb_hi, int mb_lo)
{
  const float ang = sgn * (TWO_PI / (float)T_N);
  for (int mbits = mb_hi; mbits >= mb_lo; mbits -= 2) {
    const int M = 1 << mbits;
#pragma unroll 8
    for (int v = tid; v < T_N/4; v += NT) {
      const int j = v & (M-1);
      const int base = ((v >> mbits) << (mbits+2)) | j;
      const int i0 = pad(base), i1 = pad(base+M), i2 = pad(base+2*M), i3 = pad(base+3*M);
      float2 a0=d[i0], a1=d[i1], a2=d[i2], a3=d[i3];
      float2 t0=f2add(a0,a2), t1=f2sub(a0,a2), t2=f2add(a1,a3), t3=f2sub(a1,a3);
      float2 y0=f2add(t0,t2), y2=f2sub(t0,t2);
      float2 y1=make_float2(t1.x - sgn*t3.y, t1.y + sgn*t3.x);
      float2 y3=make_float2(t1.x + sgn*t3.y, t1.y - sgn*t3.x);
      float s1,c1;
      __sincosf(ang * (float)(j << (12-mbits)), &s1, &c1);
      float c2=c1*c1-s1*s1, s2=2.f*c1*s1;
      float c3=c1*c2-s1*s2, s3=c1*s2+s1*c2;
      d[i0]=y0;
      d[i1]=cmul_cs(y1,c1,s1);
      d[i2]=cmul_cs(y2,c2,s2);
      d[i3]=cmul_cs(y3,c3,s3);
    }
    __syncthreads();
  }
}
__device__ void fold_store8(const float2* d, const float* __restrict__ phi, float* outp, int tid)
{
  const int k = tid >> 3, g = tid & 7;
  float acc = 0.f;
  for (int f = g; f < FOLD_F; f += 8) {
    float2 u = d[pad(f)];
    float w = phi[f] * ((f == 0) ? 1.f : 2.f);
    float sv, cv;
    __sincosf((TWO_PI/64.f) * (float)((f*k) & 63), &sv, &cv);
    acc += w * (u.x*cv - u.y*sv);
  }
  acc += __shfl_xor(acc, 1);
  acc += __shfl_xor(acc, 2);
  acc += __shfl_xor(acc, 4);
  if (g == 0) outp[k] = acc * INV_N;
}

// K1: xh = FFT(x) + S0 fold.
__global__ void __launch_bounds__(NT) k_fft_x(const float* __restrict__ x, const float* __restrict__ phi,
                                              float2* __restrict__ xh, float* __restrict__ out)
{
  extern __shared__ char smem[];
  float2* d = (float2*)smem;
  const int tid = threadIdx.x;
  const int b = blockIdx.x;
  const float* xr = x + b * T_N;
  for (int i = tid; i < T_N; i += NT) d[pad(i)] = make_float2(xr[i], 0.f);
  __syncthreads();
  dif_sweep(d, tid, -1.f, 12, 0);
  for (int p = tid; p < T_N; p += NT) {
    int r = rev4_14(p);
    if (p < r) { int ip = pad(p), ir = pad(r); float2 t = d[ip]; d[ip] = d[ir]; d[ir] = t; }
  }
  __syncthreads();
  float2* xrow = xh + (size_t)b * T_N;
  for (int i = tid; i < T_N; i += NT) xrow[i] = d[pad(i)];
  fold_store8(d, phi, out + b * 64, tid);
}

// Decimated order-1 body: demodulated band [lo,hi) at slots [0,W).
template<int LOGN>
__device__ __forceinline__ void o1_dec_body(v2f* sm, int sub, int t, int j1, int b,
    const float2* __restrict__ xh, const float* __restrict__ psi1,
    const float* __restrict__ phi, float2* __restrict__ u1h, float* __restrict__ out)
{
  constexpr int N = 1<<LOGN, SEGT = N/16;
  v2f* ds = sm + sub*N + ((sub*N)>>4);
  const float c = 5734.4f * exp2f(-0.125f*(float)j1);
  const int lo = max(0, (int)(0.36f*c));
  const int hi = min(T_N, (int)(1.64f*c)+2);
  const int W = hi - lo;
  const float2* xrow = xh + (size_t)b * T_N;
  const float* prow = psi1 + j1 * T_N;
#pragma unroll
  for (int s = 0; s < 16; ++s) {
    int f = t + s*SEGT;
    v2f z; z.x = 0.f; z.y = 0.f;
    if (f < W) { float2 xv = xrow[lo+f]; float p = prow[lo+f]; z.x = xv.x*p; z.y = xv.y*p; }
    ds[f + (f>>4)] = z;
  }
  __syncthreads();
  constexpr int RM = (LOGN == 9) ? 10 : 9;
  o2_body<LOGN, RM, false, 16>(ds, t);
  const int tb = TBTAB[(j1>>3) & 7];
  const float R = (float)(T_N >> LOGN);
  float2* urow = u1h + (size_t)(b*N1 + j1) * USTRIDE;
  for (int i = t; i < tb; i += SEGT) {
    v2f u = ds[i + (i>>4)];
    urow[i] = make_float2(R*u.x, R*u.y);
  }
  float* outp = out + 1024 + (size_t)(b*N1 + j1)*64;
  if constexpr (SEGT >= 64) fold_generic<SEGT/64>(ds, phi, outp, t, 1.f/(float)N);
  else                      fold32(ds, phi, outp, t, 1.f/(float)N, true);
}

// K2a (order-1, N'=8192 only): j1 0-7, 1 pipeline/block, 512 thr. 128 blocks.
__global__ void __launch_bounds__(NT, 4) k_o1a(const float2* __restrict__ xh, const float* __restrict__ psi1,
                                               const float* __restrict__ phi, float2* __restrict__ u1h,
                                               float* __restrict__ out)
{
  extern __shared__ char smem[];
  o1_dec_body<13>((v2f*)smem, 0, threadIdx.x, blockIdx.x / B_SZ, blockIdx.x % B_SZ,
                  xh, psi1, phi, u1h, out);
}

// K2b (order-1, N' <= 4096): 256-thread / 34.8KB blocks, 4 blocks/CU.
// 18 groups per batch: grp 0-7: q=1 4096 (1 ppl/blk) | 8-11: q=2 2048 (2)
// | 12-13: q=3 1024 (4) | 14-17: q>=4 512 (8).
__global__ void __launch_bounds__(NTS, 4) k_o1b(const float2* __restrict__ xh, const float* __restrict__ psi1,
                                                const float* __restrict__ phi, float2* __restrict__ u1h,
                                                float* __restrict__ out)
{
  extern __shared__ char smem[];
  v2f* sm = (v2f*)smem;
  const int grp = blockIdx.x / B_SZ, b = blockIdx.x % B_SZ;
  const int tid = threadIdx.x;
  if (grp < 8) {
    o1_dec_body<12>(sm, 0, tid, 8 + grp, b, xh, psi1, phi, u1h, out);
  } else if (grp < 12) {
    const int sub = tid >> 7;
    o1_dec_body<11>(sm, sub, tid & 127, 16 + (grp-8)*2 + sub, b, xh, psi1, phi, u1h, out);
  } else if (grp < 14) {
    const int sub = tid >> 6;
    o1_dec_body<10>(sm, sub, tid & 63, 24 + (grp-12)*4 + sub, b, xh, psi1, phi, u1h, out);
  } else {
    const int sub = tid >> 5;
    o1_dec_body<9>(sm, sub, tid & 31, 32 + (grp-14)*8 + sub, b, xh, psi1, phi, u1h, out);
  }
}

// Decimated order-2 body (S2 fold only).  Input support min(W, tb, N) — input
// past N is >= 5.6 sigma_env of the U1 envelope for affected classes.
template<int LOGN, int K1ST>
__device__ __forceinline__ void o2_cls_body(v2f* sm, int sub, int t, int b, int j1, int j2, bool valid,
    const float2* __restrict__ u1h, const float* __restrict__ psi2,
    const float* __restrict__ phi, float* __restrict__ out)
{
  constexpr int N = 1<<LOGN, SEGT = N/16;
  v2f* ds = sm + sub*N + ((sub*N)>>4);
  const int W  = WTAB[j2 & 7];
  const int tb = TBTAB[(j1 >> 3) & 7];
  const int lim = min(min(W, tb), N);
  const float2* urow = u1h + (size_t)(b * N1 + j1) * USTRIDE;
  const float* prow = psi2 + j2 * T_N;
#pragma unroll
  for (int s = 0; s < 16; ++s) {
    int f = t + s*SEGT;
    v2f z; z.x = 0.f; z.y = 0.f;
    if (valid && f < lim) { float2 u = urow[f]; float ps = prow[f]; z.x = u.x*ps; z.y = u.y*ps; }
    ds[f + (f>>4)] = z;
  }
  __syncthreads();
  constexpr int RM = ((1<<(LOGN-4)) >= 256) ? 1 : (256 >> (LOGN-4));
  constexpr bool JL = ((1<<(LOGN-4)) > 256);
  o2_body<LOGN, RM, JL, K1ST>(ds, t);
  float* outp = out + 66560 + (size_t)(b * NPAIR + pair_index(j1, j2)) * 64;
  if constexpr (SEGT >= 64) { if (valid) fold_generic<SEGT/64>(ds, phi, outp, t, 1.f/(float)N); }
  else                      fold32(ds, phi, outp, t, 1.f/(float)N, valid);
}

// K3a (order-2, j2 in {1,2}): 512-thr / 69.6KB blocks, 2 blocks/CU.
// grp 0-7: j2=1 @ 8192 (1 ppl/blk, sp8) | grp 8-15: j2=2 @ 4096 (2 ppl/blk,
// j1 = (grp-8)*2+sub covers q0+q1; lim clamps q0 input at 4096 = 5.6 sigma).
// 256 blocks -> one round, half the CU slots filled (was 25%).
__global__ void __launch_bounds__(NT, 4) k_o2a(const float2* __restrict__ u1h, const float* __restrict__ psi2,
                                               const float* __restrict__ phi, float* __restrict__ out)
{
  extern __shared__ char smem[];
  v2f* sm = (v2f*)smem;
  const int grp = blockIdx.x / B_SZ, b = blockIdx.x % B_SZ;
  const int tid = threadIdx.x;
  if (grp < 8) {
    o2_cls_body<13,8>(sm, 0, tid, b, grp, 1, true, u1h, psi2, phi, out);
  } else {
    const int sub = tid >> 8;
    o2_cls_body<12,16>(sm, sub, tid & 255, b, (grp-8)*2 + sub, 2, true, u1h, psi2, phi, out);
  }
}

// K3b (order-2, j2 >= 3): 256-thread / 34.8KB blocks, 4 blocks/CU.
// 63 groups per batch = 1008 blocks <= 1024 slots -> exactly one round.
// grp 0-23: j2=3 4096 (1/blk, j1=grp) | 24-39: j2=4 2048 (2/blk)
// | 40-49: j2=5 1024 (4/blk) | 50-55: j2=6 512 (8/blk)
// | 56-62: j2=7 512 (8/blk, j1 0-55).
__global__ void __launch_bounds__(NTS, 4) k_o2b(const float2* __restrict__ u1h, const float* __restrict__ psi2,
                                                const float* __restrict__ phi, float* __restrict__ out)
{
  extern __shared__ char smem[];
  v2f* sm = (v2f*)smem;
  const int grp = blockIdx.x / B_SZ, b = blockIdx.x % B_SZ;
  const int tid = threadIdx.x;
  if (grp < 24) {
    o2_cls_body<12,16>(sm, 0, tid, b, grp, 3, true, u1h, psi2, phi, out);
  } else if (grp < 40) {
    const int sub = tid >> 7;
    o2_cls_body<11,16>(sm, sub, tid & 127, b, (grp-24)*2 + sub, 4, true, u1h, psi2, phi, out);
  } else if (grp < 50) {
    const int sub = tid >> 6;
    o2_cls_body<10,16>(sm, sub, tid & 63, b, (grp-40)*4 + sub, 5, true, u1h, psi2, phi, out);
  } else if (grp < 56) {
    const int sub = tid >> 5;
    o2_cls_body<9,16>(sm, sub, tid & 31, b, (grp-50)*8 + sub, 6, true, u1h, psi2, phi, out);
  } else {
    const int sub = tid >> 5;
    o2_cls_body<9,8>(sm, sub, tid & 31, b, (grp-56)*8 + sub, 7, true, u1h, psi2, phi, out);
  }
}

extern "C" void kernel_launch(void* const* d_in, const int* in_sizes, int n_in,
                              void* d_out, int out_size, void* d_ws, size_t ws_size,
                              hipStream_t stream)
{
  const float* x    = (const float*)d_in[0];
  const float* psi1 = (const float*)d_in[1];
  const float* psi2 = (const float*)d_in[2];
  const float* phi  = (const float*)d_in[3];
  float* out = (float*)d_out;

  float2* xh  = (float2*)d_ws;
  float2* u1h = xh + (size_t)B_SZ * T_N;

  const size_t lds_h = (size_t)(T_N + (T_N >> 4)) * sizeof(float2);    // 139264 B (fft_x)
  const size_t lds_l = (size_t)(8192 + (8192 >> 4)) * sizeof(float2);  // 69632 B (o1a/o2a)
  const size_t lds_s = (size_t)(4096 + (4096 >> 4)) * sizeof(float2);  // 34816 B (o1b/o2b)

  (void)hipFuncSetAttribute((const void*)k_fft_x, hipFuncAttributeMaxDynamicSharedMemorySize, (int)lds_h);
  (void)hipFuncSetAttribute((const void*)k_o1a,   hipFuncAttributeMaxDynamicSharedMemorySize, (int)lds_l);
  (void)hipFuncSetAttribute((const void*)k_o1b,   hipFuncAttributeMaxDynamicSharedMemorySize, (int)lds_s);
  (void)hipFuncSetAttribute((const void*)k_o2a,   hipFuncAttributeMaxDynamicSharedMemorySize, (int)lds_l);
  (void)hipFuncSetAttribute((const void*)k_o2b,   hipFuncAttributeMaxDynamicSharedMemorySize, (int)lds_s);

  hipLaunchKernelGGL(k_fft_x, dim3(B_SZ),      dim3(NT),  lds_h, stream, x, phi, xh, out);
  hipLaunchKernelGGL(k_o1a,   dim3(B_SZ * 8),  dim3(NT),  lds_l, stream, xh, psi1, phi, u1h, out);
  hipLaunchKernelGGL(k_o1b,   dim3(B_SZ * 18), dim3(NTS), lds_s, stream, xh, psi1, phi, u1h, out);
  hipLaunchKernelGGL(k_o2a,   dim3(B_SZ * 16), dim3(NT),  lds_l, stream, u1h, psi2, phi, out);
  hipLaunchKernelGGL(k_o2b,   dim3(B_SZ * 63), dim3(NTS), lds_s, stream, u1h, psi2, phi, out);
}